// Round 10
// baseline (112.941 us; speedup 1.0000x reference)
//
#include <hip/hip_runtime.h>

// LogSignature depth-4, C=16, B=64, L=256, fp32.
// out per batch: [lvl1(16) | lvl2(256) | lvl3(4096) | lvl4(65536)] = 69904
//
// v11 = v10 + a-pair. R9: c-quad cut k_scan to 43.7us; DS/CU ~28us, VALU
// ~21us/SIMD, poorly overlapped at 2 waves/SIMD. Row-read b128s scale with
// total wave count, so one wave now covers TWO a-values (a0, a0+8): rows
// read once per wave serve 2 passes -> DS/CU ~14.7us.
// k_scan: block (j, a0<8), 128 threads = 2 h-waves; thread (b, c0) owns
//   a-pair x c-quad = 128 accum floats (s4A/s4B, 64 v2f). Streams double-
//   buffered in named register sets (ping-pong, no dynamic indexing); rows
//   via uniform ds_read_b128 broadcast from Lp. Step 255 zero-padded.
//   launch_bounds(128,1): 512-VGPR ceiling, no coerced budget (v5 lesson).
//   Epilogue: two a-rounds through the slot-65 LDS buffer (conflict-free),
//   each one coalesced 16KB write. Grid 512 blocks = 2/CU, 1 wave/SIMD.
// k_log: v4's single-stage 2-chunk Chen merge + log correction (proven).
//
// ws (floats): sigA [64][4368] | sigB [64][4368]  (~2.2 MB)

#define NC 16
#define NL 256
#define NB 64
#define OUTB 69904
#define SIG123 4368
#define OFF_L2 16
#define OFF_L3 272
#define OFF_L4 4368
#define LCS 260  // padded component-major stride

#define SIGA_OFF 0
#define SIGB_OFF (NB * SIG123)

typedef float v2f __attribute__((ext_vector_type(2)));

#define EXTRACT(V, U) ((U) == 0 ? (V).x : (U) == 1 ? (V).y : (U) == 2 ? (V).z : (V).w)

// One signature step for one a-value (S4: 4 c-quads x 16 d as v2f[4][8]).
#define STEPA(S4, S3, S2, S1, DXA, DXB, D0, D1, D2, D3, Q0, Q1, Q2, Q3)          \
    {                                                                            \
        const float P_ = (DXB) * (S1);                                           \
        const float Q_ = (DXB) * (DXA);                                          \
        const float pre4_ = fmaf(1.f / 6.f, P_, fmaf(1.f / 24.f, Q_, 0.5f * (S2))); \
        const float U_ = fmaf(0.5f, P_, fmaf(1.f / 6.f, Q_, (S2)));              \
        const float T0_ = fmaf((D0), pre4_, (S3)[0]);                            \
        const float T1_ = fmaf((D1), pre4_, (S3)[1]);                            \
        const float T2_ = fmaf((D2), pre4_, (S3)[2]);                            \
        const float T3_ = fmaf((D3), pre4_, (S3)[3]);                            \
        const v2f dv2_[8] = {{Q0.x, Q0.y}, {Q0.z, Q0.w}, {Q1.x, Q1.y}, {Q1.z, Q1.w}, \
                             {Q2.x, Q2.y}, {Q2.z, Q2.w}, {Q3.x, Q3.y}, {Q3.z, Q3.w}}; \
        const v2f Tv0_ = {T0_, T0_}, Tv1_ = {T1_, T1_}, Tv2_ = {T2_, T2_},       \
                  Tv3_ = {T3_, T3_};                                             \
        _Pragma("unroll") for (int d_ = 0; d_ < 8; ++d_) {                       \
            S4[0][d_] = __builtin_elementwise_fma(dv2_[d_], Tv0_, S4[0][d_]);    \
            S4[1][d_] = __builtin_elementwise_fma(dv2_[d_], Tv1_, S4[1][d_]);    \
            S4[2][d_] = __builtin_elementwise_fma(dv2_[d_], Tv2_, S4[2][d_]);    \
            S4[3][d_] = __builtin_elementwise_fma(dv2_[d_], Tv3_, S4[3][d_]);    \
        }                                                                        \
        (S3)[0] = fmaf((D0), U_, (S3)[0]);                                       \
        (S3)[1] = fmaf((D1), U_, (S3)[1]);                                       \
        (S3)[2] = fmaf((D2), U_, (S3)[2]);                                       \
        (S3)[3] = fmaf((D3), U_, (S3)[3]);                                       \
        (S2) = fmaf((DXB), fmaf(0.5f, (DXA), (S1)), (S2));                       \
        (S1) += (DXA);                                                           \
    }

__global__ __launch_bounds__(128, 1) void k_scan(const float* __restrict__ path,
                                                 float* __restrict__ out,
                                                 float* __restrict__ sigA,
                                                 float* __restrict__ sigB) {
    const int bid = blockIdx.x;
    const int j = bid >> 3;
    const int a0 = bid & 7;          // a-pair: (a0, a0+8)
    const int tid = threadIdx.x;
    const int h = tid >> 6;          // time chunk: 0 -> [0,128), 1 -> [128,256)
    const int b = (tid >> 2) & 15;
    const int c0 = tid & 3;          // owns c = c0, c0+4, c0+8, c0+12

    __shared__ float Lp[NL * NC];    // time-major diffs (in place over path)
    __shared__ float Lc[NC * LCS];   // component-major diffs; reused as slot-65 merge buf

    // ---- stage path[j] (16 KB, coalesced; 8 float4 per thread) ----
    const float* pj = path + (size_t)j * NL * NC;
#pragma unroll
    for (int k = 0; k < 8; ++k) {
        const int f = tid + k * 128;
        *(float4*)&Lp[f * 4] = *(const float4*)&pj[f * 4];
    }
    __syncthreads();

    // ---- diffs; step 255 zero-padded (exact identity step) ----
    float4 dif[8];
#pragma unroll
    for (int k = 0; k < 8; ++k) {
        const int f = tid + k * 128;  // float4 index 0..1023
        if (f < 1020) {
            const float4 x0 = *(const float4*)&Lp[f * 4];
            const float4 x1 = *(const float4*)&Lp[f * 4 + 16];
            dif[k] = make_float4(x1.x - x0.x, x1.y - x0.y, x1.z - x0.z, x1.w - x0.w);
        } else {
            dif[k] = make_float4(0.f, 0.f, 0.f, 0.f);
        }
    }
    __syncthreads();
#pragma unroll
    for (int k = 0; k < 8; ++k) {
        const int f = tid + k * 128;
        *(float4*)&Lp[f * 4] = dif[k];
        const int t = f >> 2;            // time index 0..255
        const int i0 = 4 * (f & 3);      // component base
        Lc[(i0 + 0) * LCS + t] = dif[k].x;
        Lc[(i0 + 1) * LCS + t] = dif[k].y;
        Lc[(i0 + 2) * LCS + t] = dif[k].z;
        Lc[(i0 + 3) * LCS + t] = dif[k].w;
    }
    __syncthreads();

    // ---- chunk-local scan: 128 steps, a-pair x c-quad accumulators ----
    v2f s4A[4][8], s4B[4][8];
#pragma unroll
    for (int m = 0; m < 4; ++m)
#pragma unroll
        for (int d = 0; d < 8; ++d) {
            s4A[m][d] = (v2f){0.f, 0.f};
            s4B[m][d] = (v2f){0.f, 0.f};
        }
    float s3qA[4] = {0.f, 0.f, 0.f, 0.f};
    float s3qB[4] = {0.f, 0.f, 0.f, 0.f};
    float s2abA = 0.f, s2abB = 0.f, s1aA = 0.f, s1aB = 0.f;

#define LOADG(VA0, VA1, VB, VC0, VC1, VC2, VC3, TT)              \
    VA0 = *(const float4*)(Lc + a0 * LCS + (TT));                \
    VA1 = *(const float4*)(Lc + (a0 + 8) * LCS + (TT));          \
    VB = *(const float4*)(Lc + b * LCS + (TT));                  \
    VC0 = *(const float4*)(Lc + c0 * LCS + (TT));                \
    VC1 = *(const float4*)(Lc + (c0 + 4) * LCS + (TT));          \
    VC2 = *(const float4*)(Lc + (c0 + 8) * LCS + (TT));          \
    VC3 = *(const float4*)(Lc + (c0 + 12) * LCS + (TT));

#define COMP4(VA0, VA1, VB, VC0, VC1, VC2, VC3, TT)                              \
    _Pragma("unroll") for (int u_ = 0; u_ < 4; ++u_) {                           \
        const float* rr_ = Lp + ((TT) + u_) * NC;                                \
        const float4 q0_ = *(const float4*)(rr_);                                \
        const float4 q1_ = *(const float4*)(rr_ + 4);                            \
        const float4 q2_ = *(const float4*)(rr_ + 8);                            \
        const float4 q3_ = *(const float4*)(rr_ + 12);                           \
        const float dxa0_ = EXTRACT(VA0, u_), dxa1_ = EXTRACT(VA1, u_);          \
        const float dxb_ = EXTRACT(VB, u_);                                      \
        const float d0_ = EXTRACT(VC0, u_), d1_ = EXTRACT(VC1, u_);              \
        const float d2_ = EXTRACT(VC2, u_), d3_ = EXTRACT(VC3, u_);              \
        STEPA(s4A, s3qA, s2abA, s1aA, dxa0_, dxb_, d0_, d1_, d2_, d3_, q0_, q1_, \
              q2_, q3_)                                                          \
        STEPA(s4B, s3qB, s2abB, s1aB, dxa1_, dxb_, d0_, d1_, d2_, d3_, q0_, q1_, \
              q2_, q3_)                                                          \
    }

    int t = h * 128;
    float4 Aa0, Aa1, Ab, Ac0, Ac1, Ac2, Ac3;
    float4 Ba0, Ba1, Bb, Bc0, Bc1, Bc2, Bc3;
    LOADG(Aa0, Aa1, Ab, Ac0, Ac1, Ac2, Ac3, t)
    for (int it = 0; it < 16; ++it, t += 8) {
        LOADG(Ba0, Ba1, Bb, Bc0, Bc1, Bc2, Bc3, t + 4)
        COMP4(Aa0, Aa1, Ab, Ac0, Ac1, Ac2, Ac3, t)
        LOADG(Aa0, Aa1, Ab, Ac0, Ac1, Ac2, Ac3, t + 8)  // final overrun reads Lc pad
        COMP4(Ba0, Ba1, Bb, Bc0, Bc1, Bc2, Bc3, t + 4)
    }
#undef LOADG
#undef COMP4

    // ---- epilogue: two a-rounds; merge A4+B4 in slot-65 LDS, one write each ----
    __syncthreads();  // main-loop Lc reads done; Lc reusable

#define EPI(S4X, AV)                                                             \
    {                                                                            \
        float* sl_ = Lc + (size_t)(b * 4 + c0) * 65;                             \
        if (h == 0) {                                                            \
            _Pragma("unroll") for (int m_ = 0; m_ < 4; ++m_)                     \
                _Pragma("unroll") for (int q_ = 0; q_ < 4; ++q_)                 \
                    *(float4*)&sl_[m_ * 16 + q_ * 4] = make_float4(              \
                        S4X[m_][2 * q_].x, S4X[m_][2 * q_].y,                    \
                        S4X[m_][2 * q_ + 1].x, S4X[m_][2 * q_ + 1].y);           \
        }                                                                        \
        __syncthreads();                                                         \
        if (h == 1) {                                                            \
            _Pragma("unroll") for (int m_ = 0; m_ < 4; ++m_)                     \
                _Pragma("unroll") for (int q_ = 0; q_ < 4; ++q_) {               \
                    float4 v_ = *(const float4*)&sl_[m_ * 16 + q_ * 4];          \
                    v_.x += S4X[m_][2 * q_].x;                                   \
                    v_.y += S4X[m_][2 * q_].y;                                   \
                    v_.z += S4X[m_][2 * q_ + 1].x;                               \
                    v_.w += S4X[m_][2 * q_ + 1].y;                               \
                    *(float4*)&sl_[m_ * 16 + q_ * 4] = v_;                       \
                }                                                                \
        }                                                                        \
        __syncthreads();                                                         \
        {                                                                        \
            float* o4_ = out + (size_t)j * OUTB + OFF_L4 + (AV) * 4096;          \
            _Pragma("unroll") for (int k_ = 0; k_ < 8; ++k_) {                   \
                const int f_ = tid + k_ * 128;                                   \
                const int m0_ = f_ * 4;                                          \
                const int bb_ = m0_ >> 8;                                        \
                const int cc_ = (m0_ >> 4) & 15;                                 \
                const int dd_ = m0_ & 15;                                        \
                const int src_ = (bb_ * 4 + (cc_ & 3)) * 65 + (cc_ >> 2) * 16 + dd_; \
                *(float4*)(o4_ + m0_) = *(const float4*)&Lc[src_];               \
            }                                                                    \
        }                                                                        \
        __syncthreads();                                                         \
    }

    EPI(s4A, a0)
    EPI(s4B, a0 + 8)
#undef EPI

    // ---- levels 1-3 of this thread's chunk (both a-values) ----
    float* sg = (h ? sigB : sigA) + (size_t)j * SIG123;
#pragma unroll
    for (int m = 0; m < 4; ++m) {
        sg[OFF_L3 + (a0 * 16 + b) * 16 + c0 + 4 * m] = s3qA[m];
        sg[OFF_L3 + ((a0 + 8) * 16 + b) * 16 + c0 + 4 * m] = s3qB[m];
    }
    if (c0 == 0) {
        sg[OFF_L2 + a0 * 16 + b] = s2abA;
        sg[OFF_L2 + (a0 + 8) * 16 + b] = s2abB;
    }
    if ((tid & 63) == 0) {
        sg[a0] = s1aA;
        sg[a0 + 8] = s1aB;
    }
}

// Chen cross-terms (S4 = [A4+B4] + A1(x)B3 + A2(x)B2 + A3(x)B1) + log
// correction. Block (j,a). Merged S1/S2/S3 in LDS (~20 KB); B3 from global
// (L2-resident). v4-proven (~8us).
__global__ __launch_bounds__(256) void k_log(const float* __restrict__ sigA,
                                             const float* __restrict__ sigB,
                                             float* __restrict__ out) {
    const int bid = blockIdx.x;
    const int j = bid >> 4;
    const int a = bid & 15;
    const int tid = threadIdx.x;
    const int q = tid >> 4;
    const int r = tid & 15;

    const float* A = sigA + (size_t)j * SIG123;
    const float* Bp = sigB + (size_t)j * SIG123;

    __shared__ float S1m[16], B1s[16], A2s[16];
    __shared__ float S2m[256], B2s[256], A3s[256];
    __shared__ float S3m[4096];

    const float b1r = Bp[r];             // B1[r]
    const float b2t = Bp[OFF_L2 + tid];  // B2[q,r]

    if (tid < 16) {
        const float bb = Bp[tid];
        B1s[tid] = bb;
        S1m[tid] = A[tid] + bb;               // S1 = A1 + B1
        A2s[tid] = A[OFF_L2 + a * 16 + tid];  // A2[a,:]
    }
    B2s[tid] = b2t;
    S2m[tid] = A[OFF_L2 + tid] + b2t + A[q] * b1r;  // S2 = A2 + B2 + A1(x)B1
    A3s[tid] = A[OFF_L3 + a * 256 + tid];           // A3[a,:,:]
#pragma unroll
    for (int k = 0; k < 16; ++k) {  // S3[p,q,r] = A3 + B3 + A1[p]B2[qr] + A2[pq]B1[r]
        const int m = k * 256 + tid;
        S3m[m] = A[OFF_L3 + m] + Bp[OFF_L3 + m] + A[k] * b2t + A[OFF_L2 + k * 16 + q] * b1r;
    }
    __syncthreads();

    const float s1a = S1m[a];
    const float A1a = A[a];
    float* outj = out + (size_t)j * OUTB;
    float* o4 = outj + OFF_L4 + a * 4096;
    const float Ac = -0.5f * s1a;

#pragma unroll
    for (int k = 0; k < 4; ++k) {
        const int f = tid + k * 256;
        const int m0 = f * 4;  // element offset: bb*256 + cc*16 + d0
        const int bb = m0 >> 8;
        const int cc = (m0 >> 4) & 15;
        const float s1b = S1m[bb], s1c = S1m[cc];
        const float s2ab = S2m[a * 16 + bb];
        const float s2bc = S2m[bb * 16 + cc];
        const float s3abc = S3m[a * 256 + (m0 >> 4)];  // merged S3[a,b,c]
        const float a3x = A3s[m0 >> 4];                // A3[a,b,c]
        const float a2x = A2s[bb];                     // A2[a,b]

        const float4 a4 = *(const float4*)(o4 + m0);            // A4+B4
        const float4 b3v = *(const float4*)(Bp + OFF_L3 + m0);  // B3[b,c,d..] (L2)
        const float4 b2v = *(const float4*)(&B2s[m0 & 255]);
        const float4 b1v = *(const float4*)(&B1s[m0 & 15]);
        const float4 v3 = *(const float4*)(&S3m[m0]);
        const float4 v2 = *(const float4*)(&S2m[m0 & 255]);
        const float4 v1 = *(const float4*)(&S1m[m0 & 15]);

        const float Bv = fmaf((1.f / 3.f) * s1a, s1b, -0.5f * s2ab);
        const float Cv = -0.5f * s3abc + (1.f / 3.f) * fmaf(s1a, s2bc, s2ab * s1c)
                         - 0.25f * s1a * s1b * s1c;
        float4 rv;
        // merged S4 = (A4+B4) + A1[a]B3[bcd] + A2[ab]B2[cd] + A3[abc]B1[d]
        rv.x = a4.x + fmaf(A1a, b3v.x, fmaf(a2x, b2v.x, a3x * b1v.x));
        rv.y = a4.y + fmaf(A1a, b3v.y, fmaf(a2x, b2v.y, a3x * b1v.y));
        rv.z = a4.z + fmaf(A1a, b3v.z, fmaf(a2x, b2v.z, a3x * b1v.z));
        rv.w = a4.w + fmaf(A1a, b3v.w, fmaf(a2x, b2v.w, a3x * b1v.w));
        // log correction
        rv.x = fmaf(Ac, v3.x, rv.x) + fmaf(Bv, v2.x, Cv * v1.x);
        rv.y = fmaf(Ac, v3.y, rv.y) + fmaf(Bv, v2.y, Cv * v1.y);
        rv.z = fmaf(Ac, v3.z, rv.z) + fmaf(Bv, v2.z, Cv * v1.z);
        rv.w = fmaf(Ac, v3.w, rv.w) + fmaf(Bv, v2.w, Cv * v1.w);
        *(float4*)(o4 + m0) = rv;
    }

    // level 3 (coalesced)
    {
        const float s1b = S1m[q], s1c = S1m[r];
        const float s2ab = S2m[a * 16 + q];
        const float s2bc = S2m[q * 16 + r];
        const float s3abc = S3m[a * 256 + tid];
        const float r3 = s3abc - 0.5f * fmaf(s1a, s2bc, s2ab * s1c)
                         + (1.f / 3.f) * s1a * s1b * s1c;
        outj[OFF_L3 + a * 256 + tid] = r3;
    }
    // level 2
    if (tid < 16) outj[OFF_L2 + a * 16 + tid] = fmaf(-0.5f * s1a, S1m[tid], S2m[a * 16 + tid]);
    // level 1
    if (tid == 0) outj[a] = s1a;
}

extern "C" void kernel_launch(void* const* d_in, const int* in_sizes, int n_in,
                              void* d_out, int out_size, void* d_ws, size_t ws_size,
                              hipStream_t stream) {
    const float* path = (const float*)d_in[0];
    float* out = (float*)d_out;
    float* ws = (float*)d_ws;
    float* sigA = ws + SIGA_OFF;
    float* sigB = ws + SIGB_OFF;

    k_scan<<<NB * 8, 128, 0, stream>>>(path, out, sigA, sigB);
    k_log<<<NB * 16, 256, 0, stream>>>(sigA, sigB, out);
}

// Round 11
// 108.566 us; speedup vs baseline: 1.0403x; 1.0403x over previous
//
#include <hip/hip_runtime.h>

// LogSignature depth-4, C=16, B=64, L=256, fp32.
// out per batch: [lvl1(16) | lvl2(256) | lvl3(4096) | lvl4(65536)] = 69904
//
// v12 = v10 (best: 43.7us k_scan) + two surgical changes.
// R10 refuted a-pair (1 wave/SIMD starves overlap); R8 refuted >16 waves/CU
// (DS-bound); v10's gap to the ~28us/CU DS floor is overlap bubbles at
// 2 waves/SIMD plus scalarized accum FMAs (~90 VALU issues/step measured).
//  (1) inline-asm v_pk_fma_f32 for the 32 accumulator FMAs (compiler was
//      scalarizing __builtin_elementwise_fma): VALU/step ~90 -> ~58.
//  (2) LDS compacted to exactly 32768 B -> 5 blocks/CU (2.5 waves/SIMD,
//      +25% waves): packed stream layout Lc2[t/4][16][4] (16 KB) replaces
//      the 16.6 KB padded [16][260]. Bank-safe: c-quad reads hit 4 distinct
//      bank-quads, b-read 2-way (free), a-read broadcast.
// k_scan: block (j,a), 128 threads = {h(1b)|b(4b)|c0(2b)}, 2 h-waves; thread
//   owns c-quad {c0,c0+4,c0+8,c0+12} (A=64). Rows via uniform ds_read_b128
//   broadcast from Lp; step 255 zero-padded. Epilogue: A4+B4 merged in
//   slot-65 LDS layout, one coalesced 16KB write.
// k_log: v4's single-stage 2-chunk Chen merge + log correction (proven).
//
// ws (floats): sigA [64][4368] | sigB [64][4368]  (~2.2 MB)

#define NC 16
#define NL 256
#define NB 64
#define OUTB 69904
#define SIG123 4368
#define OFF_L2 16
#define OFF_L3 272
#define OFF_L4 4368

#define SIGA_OFF 0
#define SIGB_OFF (NB * SIG123)

typedef float v2f __attribute__((ext_vector_type(2)));

// acc = a*b + acc, packed 2xfp32 (VOP3P). All operands 64-bit VGPR pairs.
#define PKFMA(ACC, A, B) \
    asm("v_pk_fma_f32 %0, %1, %2, %0" : "+v"(ACC) : "v"(A), "v"(B))

__global__ __launch_bounds__(128, 2) void k_scan(const float* __restrict__ path,
                                                 float* __restrict__ out,
                                                 float* __restrict__ sigA,
                                                 float* __restrict__ sigB) {
    const int bid = blockIdx.x;
    const int j = bid >> 4;
    const int a = bid & 15;
    const int tid = threadIdx.x;
    const int h = tid >> 6;          // time chunk: 0 -> [0,128), 1 -> [128,256)
    const int b = (tid >> 2) & 15;
    const int c0 = tid & 3;          // owns c = c0, c0+4, c0+8, c0+12

    // 32768 B total: Lp = SH[0..4095] (time-major diffs, in place over path);
    // Lc2 = SH[4096..8191] (packed streams [t/4][16][4]);
    // epilogue slot-65 buffer = SH[0..4159] (both dead by then).
    __shared__ float SH[8192];
    float* Lp = SH;
    float* Sc = SH + 4096;

    // ---- stage path[j] (16 KB, coalesced; 8 float4 per thread) ----
    const float* pj = path + (size_t)j * NL * NC;
#pragma unroll
    for (int k = 0; k < 8; ++k) {
        const int f = tid + k * 128;
        *(float4*)&Lp[f * 4] = *(const float4*)&pj[f * 4];
    }
    __syncthreads();

    // ---- diffs; step 255 zero-padded (exact identity step) ----
    float4 dif[8];
#pragma unroll
    for (int k = 0; k < 8; ++k) {
        const int f = tid + k * 128;  // float4 index 0..1023 over [t][i]
        if (f < 1020) {
            const float4 x0 = *(const float4*)&Lp[f * 4];
            const float4 x1 = *(const float4*)&Lp[f * 4 + 16];
            dif[k] = make_float4(x1.x - x0.x, x1.y - x0.y, x1.z - x0.z, x1.w - x0.w);
        } else {
            dif[k] = make_float4(0.f, 0.f, 0.f, 0.f);
        }
    }
    __syncthreads();
#pragma unroll
    for (int k = 0; k < 8; ++k) {
        const int f = tid + k * 128;
        *(float4*)&Lp[f * 4] = dif[k];
        const int t = f >> 2;            // time index 0..255
        const int i0 = 4 * (f & 3);      // component base
        // packed stream layout: Sc[(t/4)*64 + i*4 + (t&3)]
        const int sb = (t >> 2) * 64 + (t & 3);
        Sc[sb + (i0 + 0) * 4] = dif[k].x;
        Sc[sb + (i0 + 1) * 4] = dif[k].y;
        Sc[sb + (i0 + 2) * 4] = dif[k].z;
        Sc[sb + (i0 + 3) * 4] = dif[k].w;
    }
    __syncthreads();

    // ---- chunk-local scan: 128 steps, c-quad accumulators ----
    v2f s4q[4][8];
#pragma unroll
    for (int m = 0; m < 4; ++m)
#pragma unroll
        for (int d = 0; d < 8; ++d) s4q[m][d] = (v2f){0.f, 0.f};
    float s3q[4] = {0.f, 0.f, 0.f, 0.f};
    float s2ab = 0.f, s1a = 0.f;

    auto body = [&](const float4& q0, const float4& q1, const float4& q2,
                    const float4& q3, float dxa, float dxb, float dc0, float dc1,
                    float dc2, float dc3) {
        const float P = dxb * s1a;
        const float Q = dxb * dxa;
        const float pre4 = fmaf(1.f / 6.f, P, fmaf(1.f / 24.f, Q, 0.5f * s2ab));
        const float U = fmaf(0.5f, P, fmaf(1.f / 6.f, Q, s2ab));
        const float T0 = fmaf(dc0, pre4, s3q[0]);
        const float T1 = fmaf(dc1, pre4, s3q[1]);
        const float T2 = fmaf(dc2, pre4, s3q[2]);
        const float T3 = fmaf(dc3, pre4, s3q[3]);
        const v2f dv2[8] = {{q0.x, q0.y}, {q0.z, q0.w}, {q1.x, q1.y}, {q1.z, q1.w},
                            {q2.x, q2.y}, {q2.z, q2.w}, {q3.x, q3.y}, {q3.z, q3.w}};
        const v2f Tv0 = {T0, T0}, Tv1 = {T1, T1}, Tv2 = {T2, T2}, Tv3 = {T3, T3};
#pragma unroll
        for (int d = 0; d < 8; ++d) {
            PKFMA(s4q[0][d], dv2[d], Tv0);
            PKFMA(s4q[1][d], dv2[d], Tv1);
            PKFMA(s4q[2][d], dv2[d], Tv2);
            PKFMA(s4q[3][d], dv2[d], Tv3);
        }
        s3q[0] = fmaf(dc0, U, s3q[0]);
        s3q[1] = fmaf(dc1, U, s3q[1]);
        s3q[2] = fmaf(dc2, U, s3q[2]);
        s3q[3] = fmaf(dc3, U, s3q[3]);
        s2ab = fmaf(dxb, fmaf(0.5f, dxa, s1a), s2ab);
        s1a += dxa;
    };

    int t = h * 128;
    for (int it = 0; it < 32; ++it, t += 4) {
        const float* g = Sc + (t >> 2) * 64;  // this 4-step group
        const float4 va = *(const float4*)(g + a * 4);          // broadcast
        const float4 vb = *(const float4*)(g + b * 4);          // 2-way (free)
        const float4 vc0 = *(const float4*)(g + c0 * 4);        // 4 bank-quads
        const float4 vc1 = *(const float4*)(g + c0 * 4 + 16);
        const float4 vc2 = *(const float4*)(g + c0 * 4 + 32);
        const float4 vc3 = *(const float4*)(g + c0 * 4 + 48);
#pragma unroll
        for (int u = 0; u < 4; ++u) {
            const float* r = Lp + (t + u) * NC;   // uniform row, b128 broadcast
            const float4 q0 = *(const float4*)(r);
            const float4 q1 = *(const float4*)(r + 4);
            const float4 q2 = *(const float4*)(r + 8);
            const float4 q3 = *(const float4*)(r + 12);
            const float dxa = (u == 0) ? va.x : (u == 1) ? va.y : (u == 2) ? va.z : va.w;
            const float dxb = (u == 0) ? vb.x : (u == 1) ? vb.y : (u == 2) ? vb.z : vb.w;
            const float d0 = (u == 0) ? vc0.x : (u == 1) ? vc0.y : (u == 2) ? vc0.z : vc0.w;
            const float d1 = (u == 0) ? vc1.x : (u == 1) ? vc1.y : (u == 2) ? vc1.z : vc1.w;
            const float d2 = (u == 0) ? vc2.x : (u == 1) ? vc2.y : (u == 2) ? vc2.z : vc2.w;
            const float d3 = (u == 0) ? vc3.x : (u == 1) ? vc3.y : (u == 2) ? vc3.z : vc3.w;
            body(q0, q1, q2, q3, dxa, dxb, d0, d1, d2, d3);
        }
    }

    // ---- epilogue: merge A4+B4 in slot-65 LDS layout (conflict-free) ----
    // slot = b*4 + c0 (0..63); within slot: m*16 + d (m = c>>2). SH reused.
    __syncthreads();
    float* sl = SH + (size_t)(b * 4 + c0) * 65;
    if (h == 0) {
#pragma unroll
        for (int m = 0; m < 4; ++m)
#pragma unroll
            for (int q = 0; q < 4; ++q)
                *(float4*)&sl[m * 16 + q * 4] =
                    make_float4(s4q[m][2 * q].x, s4q[m][2 * q].y,
                                s4q[m][2 * q + 1].x, s4q[m][2 * q + 1].y);
    }
    __syncthreads();
    if (h == 1) {
#pragma unroll
        for (int m = 0; m < 4; ++m)
#pragma unroll
            for (int q = 0; q < 4; ++q) {
                float4 v = *(const float4*)&sl[m * 16 + q * 4];
                v.x += s4q[m][2 * q].x;
                v.y += s4q[m][2 * q].y;
                v.z += s4q[m][2 * q + 1].x;
                v.w += s4q[m][2 * q + 1].y;
                *(float4*)&sl[m * 16 + q * 4] = v;
            }
    }
    __syncthreads();
    {
        float* o4 = out + (size_t)j * OUTB + OFF_L4 + a * 4096;
#pragma unroll
        for (int k = 0; k < 8; ++k) {
            const int f = tid + k * 128;  // float4 index 0..1023
            const int m0 = f * 4;         // element offset: bb*256 + cc*16 + dd
            const int bb = m0 >> 8;
            const int cc = (m0 >> 4) & 15;
            const int dd = m0 & 15;
            const int src = (bb * 4 + (cc & 3)) * 65 + (cc >> 2) * 16 + dd;
            *(float4*)(o4 + m0) = *(const float4*)&SH[src];
        }
    }

    // ---- levels 1-3 of this thread's chunk ----
    float* sg = (h ? sigB : sigA) + (size_t)j * SIG123;
#pragma unroll
    for (int m = 0; m < 4; ++m)
        sg[OFF_L3 + (a * 16 + b) * 16 + c0 + 4 * m] = s3q[m];
    if (c0 == 0) sg[OFF_L2 + a * 16 + b] = s2ab;
    if ((tid & 63) == 0) sg[a] = s1a;
}

// Chen cross-terms (S4 = [A4+B4] + A1(x)B3 + A2(x)B2 + A3(x)B1) + log
// correction. Block (j,a). Merged S1/S2/S3 in LDS (~20 KB); B3 from global
// (L2-resident). v4-proven.
__global__ __launch_bounds__(256) void k_log(const float* __restrict__ sigA,
                                             const float* __restrict__ sigB,
                                             float* __restrict__ out) {
    const int bid = blockIdx.x;
    const int j = bid >> 4;
    const int a = bid & 15;
    const int tid = threadIdx.x;
    const int q = tid >> 4;
    const int r = tid & 15;

    const float* A = sigA + (size_t)j * SIG123;
    const float* Bp = sigB + (size_t)j * SIG123;

    __shared__ float S1m[16], B1s[16], A2s[16];
    __shared__ float S2m[256], B2s[256], A3s[256];
    __shared__ float S3m[4096];

    const float b1r = Bp[r];             // B1[r]
    const float b2t = Bp[OFF_L2 + tid];  // B2[q,r]

    if (tid < 16) {
        const float bb = Bp[tid];
        B1s[tid] = bb;
        S1m[tid] = A[tid] + bb;               // S1 = A1 + B1
        A2s[tid] = A[OFF_L2 + a * 16 + tid];  // A2[a,:]
    }
    B2s[tid] = b2t;
    S2m[tid] = A[OFF_L2 + tid] + b2t + A[q] * b1r;  // S2 = A2 + B2 + A1(x)B1
    A3s[tid] = A[OFF_L3 + a * 256 + tid];           // A3[a,:,:]
#pragma unroll
    for (int k = 0; k < 16; ++k) {  // S3[p,q,r] = A3 + B3 + A1[p]B2[qr] + A2[pq]B1[r]
        const int m = k * 256 + tid;
        S3m[m] = A[OFF_L3 + m] + Bp[OFF_L3 + m] + A[k] * b2t + A[OFF_L2 + k * 16 + q] * b1r;
    }
    __syncthreads();

    const float s1a = S1m[a];
    const float A1a = A[a];
    float* outj = out + (size_t)j * OUTB;
    float* o4 = outj + OFF_L4 + a * 4096;
    const float Ac = -0.5f * s1a;

#pragma unroll
    for (int k = 0; k < 4; ++k) {
        const int f = tid + k * 256;
        const int m0 = f * 4;  // element offset: bb*256 + cc*16 + d0
        const int bb = m0 >> 8;
        const int cc = (m0 >> 4) & 15;
        const float s1b = S1m[bb], s1c = S1m[cc];
        const float s2ab = S2m[a * 16 + bb];
        const float s2bc = S2m[bb * 16 + cc];
        const float s3abc = S3m[a * 256 + (m0 >> 4)];  // merged S3[a,b,c]
        const float a3x = A3s[m0 >> 4];                // A3[a,b,c]
        const float a2x = A2s[bb];                     // A2[a,b]

        const float4 a4 = *(const float4*)(o4 + m0);            // A4+B4
        const float4 b3v = *(const float4*)(Bp + OFF_L3 + m0);  // B3[b,c,d..] (L2)
        const float4 b2v = *(const float4*)(&B2s[m0 & 255]);
        const float4 b1v = *(const float4*)(&B1s[m0 & 15]);
        const float4 v3 = *(const float4*)(&S3m[m0]);
        const float4 v2 = *(const float4*)(&S2m[m0 & 255]);
        const float4 v1 = *(const float4*)(&S1m[m0 & 15]);

        const float Bv = fmaf((1.f / 3.f) * s1a, s1b, -0.5f * s2ab);
        const float Cv = -0.5f * s3abc + (1.f / 3.f) * fmaf(s1a, s2bc, s2ab * s1c)
                         - 0.25f * s1a * s1b * s1c;
        float4 rv;
        // merged S4 = (A4+B4) + A1[a]B3[bcd] + A2[ab]B2[cd] + A3[abc]B1[d]
        rv.x = a4.x + fmaf(A1a, b3v.x, fmaf(a2x, b2v.x, a3x * b1v.x));
        rv.y = a4.y + fmaf(A1a, b3v.y, fmaf(a2x, b2v.y, a3x * b1v.y));
        rv.z = a4.z + fmaf(A1a, b3v.z, fmaf(a2x, b2v.z, a3x * b1v.z));
        rv.w = a4.w + fmaf(A1a, b3v.w, fmaf(a2x, b2v.w, a3x * b1v.w));
        // log correction
        rv.x = fmaf(Ac, v3.x, rv.x) + fmaf(Bv, v2.x, Cv * v1.x);
        rv.y = fmaf(Ac, v3.y, rv.y) + fmaf(Bv, v2.y, Cv * v1.y);
        rv.z = fmaf(Ac, v3.z, rv.z) + fmaf(Bv, v2.z, Cv * v1.z);
        rv.w = fmaf(Ac, v3.w, rv.w) + fmaf(Bv, v2.w, Cv * v1.w);
        *(float4*)(o4 + m0) = rv;
    }

    // level 3 (coalesced)
    {
        const float s1b = S1m[q], s1c = S1m[r];
        const float s2ab = S2m[a * 16 + q];
        const float s2bc = S2m[q * 16 + r];
        const float s3abc = S3m[a * 256 + tid];
        const float r3 = s3abc - 0.5f * fmaf(s1a, s2bc, s2ab * s1c)
                         + (1.f / 3.f) * s1a * s1b * s1c;
        outj[OFF_L3 + a * 256 + tid] = r3;
    }
    // level 2
    if (tid < 16) outj[OFF_L2 + a * 16 + tid] = fmaf(-0.5f * s1a, S1m[tid], S2m[a * 16 + tid]);
    // level 1
    if (tid == 0) outj[a] = s1a;
}

extern "C" void kernel_launch(void* const* d_in, const int* in_sizes, int n_in,
                              void* d_out, int out_size, void* d_ws, size_t ws_size,
                              hipStream_t stream) {
    const float* path = (const float*)d_in[0];
    float* out = (float*)d_out;
    float* ws = (float*)d_ws;
    float* sigA = ws + SIGA_OFF;
    float* sigB = ws + SIGB_OFF;

    k_scan<<<NB * 16, 128, 0, stream>>>(path, out, sigA, sigB);
    k_log<<<NB * 16, 256, 0, stream>>>(sigA, sigB, out);
}

// Round 12
// 106.989 us; speedup vs baseline: 1.0556x; 1.0147x over previous
//
#include <hip/hip_runtime.h>

// LogSignature depth-4, C=16, B=64, L=256, fp32.
// out per batch: [lvl1(16) | lvl2(256) | lvl3(4096) | lvl4(65536)] = 69904
//
// v13 = v10 (best k_scan: 43.7us) + ONE isolated change: LDS compacted to
// exactly 32768 B -> 5 blocks/CU (10 waves/CU, 2.5/SIMD vs v10's 2).
// R11 bundled this with inline-asm pk_fma and regressed; the asm (a latency
// black box that defeats the compiler's ds_read/FMA pipelining) is the
// suspected culprit, so v13 keeps v10's compiler-scheduled FMA body verbatim.
// Lc is now stride-256 (4096 floats, no pad) with an XOR group-swizzle
// (element (i,t) at i*256 + ((g^(i&7))<<2) + (t&3), g=t>>2): the per-lane
// vb read spreads over 8 bank-groups (2-way = free), vc/va stay broadcasts,
// writes are 2-way. Swizzle is bijective per row -> bit-identical math.
// k_scan: block (j,a), 128 threads = {h(1b)|b(4b)|c0(2b)}, 2 h-waves; thread
//   owns c-quad {c0,c0+4,c0+8,c0+12} (A=64). Rows via uniform ds_read_b128
//   broadcast from Lp; step 255 zero-padded. Epilogue: A4+B4 merged in
//   slot-65 LDS layout (SH[0..4159], Lp dead), one coalesced 16KB write.
// k_log: v4's single-stage 2-chunk Chen merge + log correction (proven).
//
// ws (floats): sigA [64][4368] | sigB [64][4368]  (~2.2 MB)

#define NC 16
#define NL 256
#define NB 64
#define OUTB 69904
#define SIG123 4368
#define OFF_L2 16
#define OFF_L3 272
#define OFF_L4 4368

#define SIGA_OFF 0
#define SIGB_OFF (NB * SIG123)

typedef float v2f __attribute__((ext_vector_type(2)));

__global__ __launch_bounds__(128, 2) void k_scan(const float* __restrict__ path,
                                                 float* __restrict__ out,
                                                 float* __restrict__ sigA,
                                                 float* __restrict__ sigB) {
    const int bid = blockIdx.x;
    const int j = bid >> 4;
    const int a = bid & 15;
    const int tid = threadIdx.x;
    const int h = tid >> 6;          // time chunk: 0 -> [0,128), 1 -> [128,256)
    const int b = (tid >> 2) & 15;
    const int c0 = tid & 3;          // owns c = c0, c0+4, c0+8, c0+12

    // 32768 B total: Lp = SH[0..4095] (time-major diffs, in place over path);
    // Lc = SH[4096..8191] (swizzled component-major streams);
    // epilogue slot-65 buffer = SH[0..4159] (Lp and Lc dead by then).
    __shared__ float SH[8192];
    float* Lp = SH;
    float* Lc = SH + 4096;

    // ---- stage path[j] (16 KB, coalesced; 8 float4 per thread) ----
    const float* pj = path + (size_t)j * NL * NC;
#pragma unroll
    for (int k = 0; k < 8; ++k) {
        const int f = tid + k * 128;
        *(float4*)&Lp[f * 4] = *(const float4*)&pj[f * 4];
    }
    __syncthreads();

    // ---- diffs; step 255 zero-padded (exact identity step) ----
    float4 dif[8];
#pragma unroll
    for (int k = 0; k < 8; ++k) {
        const int f = tid + k * 128;  // float4 index 0..1023 over [t][i]
        if (f < 1020) {
            const float4 x0 = *(const float4*)&Lp[f * 4];
            const float4 x1 = *(const float4*)&Lp[f * 4 + 16];
            dif[k] = make_float4(x1.x - x0.x, x1.y - x0.y, x1.z - x0.z, x1.w - x0.w);
        } else {
            dif[k] = make_float4(0.f, 0.f, 0.f, 0.f);
        }
    }
    __syncthreads();
#pragma unroll
    for (int k = 0; k < 8; ++k) {
        const int f = tid + k * 128;
        *(float4*)&Lp[f * 4] = dif[k];
        const int t = f >> 2;            // time index 0..255
        const int i0 = 4 * (f & 3);      // component base
        const int g = t >> 2;            // group 0..63
        const int u = t & 3;
        // element (i,t) lives at Lc[i*256 + ((g ^ (i&7))<<2) + u]
        Lc[(i0 + 0) * 256 + (((g ^ ((i0 + 0) & 7)) << 2) | u)] = dif[k].x;
        Lc[(i0 + 1) * 256 + (((g ^ ((i0 + 1) & 7)) << 2) | u)] = dif[k].y;
        Lc[(i0 + 2) * 256 + (((g ^ ((i0 + 2) & 7)) << 2) | u)] = dif[k].z;
        Lc[(i0 + 3) * 256 + (((g ^ ((i0 + 3) & 7)) << 2) | u)] = dif[k].w;
    }
    __syncthreads();

    // ---- chunk-local scan: 128 steps, c-quad accumulators ----
    v2f s4q[4][8];
#pragma unroll
    for (int m = 0; m < 4; ++m)
#pragma unroll
        for (int d = 0; d < 8; ++d) s4q[m][d] = (v2f){0.f, 0.f};
    float s3q[4] = {0.f, 0.f, 0.f, 0.f};
    float s2ab = 0.f, s1a = 0.f;

    auto body = [&](const float4& q0, const float4& q1, const float4& q2,
                    const float4& q3, float dxa, float dxb, float dc0, float dc1,
                    float dc2, float dc3) {
        const float P = dxb * s1a;
        const float Q = dxb * dxa;
        const float pre4 = fmaf(1.f / 6.f, P, fmaf(1.f / 24.f, Q, 0.5f * s2ab));
        const float U = fmaf(0.5f, P, fmaf(1.f / 6.f, Q, s2ab));
        const float T0 = fmaf(dc0, pre4, s3q[0]);
        const float T1 = fmaf(dc1, pre4, s3q[1]);
        const float T2 = fmaf(dc2, pre4, s3q[2]);
        const float T3 = fmaf(dc3, pre4, s3q[3]);
        const v2f dv2[8] = {{q0.x, q0.y}, {q0.z, q0.w}, {q1.x, q1.y}, {q1.z, q1.w},
                            {q2.x, q2.y}, {q2.z, q2.w}, {q3.x, q3.y}, {q3.z, q3.w}};
        const v2f Tv0 = {T0, T0}, Tv1 = {T1, T1}, Tv2 = {T2, T2}, Tv3 = {T3, T3};
#pragma unroll
        for (int d = 0; d < 8; ++d) {
            s4q[0][d] = __builtin_elementwise_fma(dv2[d], Tv0, s4q[0][d]);
            s4q[1][d] = __builtin_elementwise_fma(dv2[d], Tv1, s4q[1][d]);
            s4q[2][d] = __builtin_elementwise_fma(dv2[d], Tv2, s4q[2][d]);
            s4q[3][d] = __builtin_elementwise_fma(dv2[d], Tv3, s4q[3][d]);
        }
        s3q[0] = fmaf(dc0, U, s3q[0]);
        s3q[1] = fmaf(dc1, U, s3q[1]);
        s3q[2] = fmaf(dc2, U, s3q[2]);
        s3q[3] = fmaf(dc3, U, s3q[3]);
        s2ab = fmaf(dxb, fmaf(0.5f, dxa, s1a), s2ab);
        s1a += dxa;
    };

    int t = h * 128;
    for (int it = 0; it < 32; ++it, t += 4) {
        const int g = t >> 2;  // 4-step group index
        const float4 va = *(const float4*)(Lc + a * 256 + ((g ^ (a & 7)) << 2));
        const float4 vb = *(const float4*)(Lc + b * 256 + ((g ^ (b & 7)) << 2));
        const float4 vc0 = *(const float4*)(Lc + c0 * 256 + ((g ^ c0) << 2));
        const float4 vc1 = *(const float4*)(Lc + (c0 + 4) * 256 + ((g ^ (c0 + 4)) << 2));
        const float4 vc2 = *(const float4*)(Lc + (c0 + 8) * 256 + ((g ^ c0) << 2));
        const float4 vc3 = *(const float4*)(Lc + (c0 + 12) * 256 + ((g ^ (c0 + 4)) << 2));
#pragma unroll
        for (int u = 0; u < 4; ++u) {
            const float* r = Lp + (t + u) * NC;   // uniform row, b128 broadcast
            const float4 q0 = *(const float4*)(r);
            const float4 q1 = *(const float4*)(r + 4);
            const float4 q2 = *(const float4*)(r + 8);
            const float4 q3 = *(const float4*)(r + 12);
            const float dxa = (u == 0) ? va.x : (u == 1) ? va.y : (u == 2) ? va.z : va.w;
            const float dxb = (u == 0) ? vb.x : (u == 1) ? vb.y : (u == 2) ? vb.z : vb.w;
            const float d0 = (u == 0) ? vc0.x : (u == 1) ? vc0.y : (u == 2) ? vc0.z : vc0.w;
            const float d1 = (u == 0) ? vc1.x : (u == 1) ? vc1.y : (u == 2) ? vc1.z : vc1.w;
            const float d2 = (u == 0) ? vc2.x : (u == 1) ? vc2.y : (u == 2) ? vc2.z : vc2.w;
            const float d3 = (u == 0) ? vc3.x : (u == 1) ? vc3.y : (u == 2) ? vc3.z : vc3.w;
            body(q0, q1, q2, q3, dxa, dxb, d0, d1, d2, d3);
        }
    }

    // ---- epilogue: merge A4+B4 in slot-65 LDS layout (conflict-free) ----
    // slot = b*4 + c0 (0..63); within slot: m*16 + d (m = c>>2). SH reused.
    __syncthreads();
    float* sl = SH + (size_t)(b * 4 + c0) * 65;
    if (h == 0) {
#pragma unroll
        for (int m = 0; m < 4; ++m)
#pragma unroll
            for (int q = 0; q < 4; ++q)
                *(float4*)&sl[m * 16 + q * 4] =
                    make_float4(s4q[m][2 * q].x, s4q[m][2 * q].y,
                                s4q[m][2 * q + 1].x, s4q[m][2 * q + 1].y);
    }
    __syncthreads();
    if (h == 1) {
#pragma unroll
        for (int m = 0; m < 4; ++m)
#pragma unroll
            for (int q = 0; q < 4; ++q) {
                float4 v = *(const float4*)&sl[m * 16 + q * 4];
                v.x += s4q[m][2 * q].x;
                v.y += s4q[m][2 * q].y;
                v.z += s4q[m][2 * q + 1].x;
                v.w += s4q[m][2 * q + 1].y;
                *(float4*)&sl[m * 16 + q * 4] = v;
            }
    }
    __syncthreads();
    {
        float* o4 = out + (size_t)j * OUTB + OFF_L4 + a * 4096;
#pragma unroll
        for (int k = 0; k < 8; ++k) {
            const int f = tid + k * 128;  // float4 index 0..1023
            const int m0 = f * 4;         // element offset: bb*256 + cc*16 + dd
            const int bb = m0 >> 8;
            const int cc = (m0 >> 4) & 15;
            const int dd = m0 & 15;
            const int src = (bb * 4 + (cc & 3)) * 65 + (cc >> 2) * 16 + dd;
            *(float4*)(o4 + m0) = *(const float4*)&SH[src];
        }
    }

    // ---- levels 1-3 of this thread's chunk ----
    float* sg = (h ? sigB : sigA) + (size_t)j * SIG123;
#pragma unroll
    for (int m = 0; m < 4; ++m)
        sg[OFF_L3 + (a * 16 + b) * 16 + c0 + 4 * m] = s3q[m];
    if (c0 == 0) sg[OFF_L2 + a * 16 + b] = s2ab;
    if ((tid & 63) == 0) sg[a] = s1a;
}

// Chen cross-terms (S4 = [A4+B4] + A1(x)B3 + A2(x)B2 + A3(x)B1) + log
// correction. Block (j,a). Merged S1/S2/S3 in LDS (~20 KB); B3 from global
// (L2-resident). v4-proven.
__global__ __launch_bounds__(256) void k_log(const float* __restrict__ sigA,
                                             const float* __restrict__ sigB,
                                             float* __restrict__ out) {
    const int bid = blockIdx.x;
    const int j = bid >> 4;
    const int a = bid & 15;
    const int tid = threadIdx.x;
    const int q = tid >> 4;
    const int r = tid & 15;

    const float* A = sigA + (size_t)j * SIG123;
    const float* Bp = sigB + (size_t)j * SIG123;

    __shared__ float S1m[16], B1s[16], A2s[16];
    __shared__ float S2m[256], B2s[256], A3s[256];
    __shared__ float S3m[4096];

    const float b1r = Bp[r];             // B1[r]
    const float b2t = Bp[OFF_L2 + tid];  // B2[q,r]

    if (tid < 16) {
        const float bb = Bp[tid];
        B1s[tid] = bb;
        S1m[tid] = A[tid] + bb;               // S1 = A1 + B1
        A2s[tid] = A[OFF_L2 + a * 16 + tid];  // A2[a,:]
    }
    B2s[tid] = b2t;
    S2m[tid] = A[OFF_L2 + tid] + b2t + A[q] * b1r;  // S2 = A2 + B2 + A1(x)B1
    A3s[tid] = A[OFF_L3 + a * 256 + tid];           // A3[a,:,:]
#pragma unroll
    for (int k = 0; k < 16; ++k) {  // S3[p,q,r] = A3 + B3 + A1[p]B2[qr] + A2[pq]B1[r]
        const int m = k * 256 + tid;
        S3m[m] = A[OFF_L3 + m] + Bp[OFF_L3 + m] + A[k] * b2t + A[OFF_L2 + k * 16 + q] * b1r;
    }
    __syncthreads();

    const float s1a = S1m[a];
    const float A1a = A[a];
    float* outj = out + (size_t)j * OUTB;
    float* o4 = outj + OFF_L4 + a * 4096;
    const float Ac = -0.5f * s1a;

#pragma unroll
    for (int k = 0; k < 4; ++k) {
        const int f = tid + k * 256;
        const int m0 = f * 4;  // element offset: bb*256 + cc*16 + d0
        const int bb = m0 >> 8;
        const int cc = (m0 >> 4) & 15;
        const float s1b = S1m[bb], s1c = S1m[cc];
        const float s2ab = S2m[a * 16 + bb];
        const float s2bc = S2m[bb * 16 + cc];
        const float s3abc = S3m[a * 256 + (m0 >> 4)];  // merged S3[a,b,c]
        const float a3x = A3s[m0 >> 4];                // A3[a,b,c]
        const float a2x = A2s[bb];                     // A2[a,b]

        const float4 a4 = *(const float4*)(o4 + m0);            // A4+B4
        const float4 b3v = *(const float4*)(Bp + OFF_L3 + m0);  // B3[b,c,d..] (L2)
        const float4 b2v = *(const float4*)(&B2s[m0 & 255]);
        const float4 b1v = *(const float4*)(&B1s[m0 & 15]);
        const float4 v3 = *(const float4*)(&S3m[m0]);
        const float4 v2 = *(const float4*)(&S2m[m0 & 255]);
        const float4 v1 = *(const float4*)(&S1m[m0 & 15]);

        const float Bv = fmaf((1.f / 3.f) * s1a, s1b, -0.5f * s2ab);
        const float Cv = -0.5f * s3abc + (1.f / 3.f) * fmaf(s1a, s2bc, s2ab * s1c)
                         - 0.25f * s1a * s1b * s1c;
        float4 rv;
        // merged S4 = (A4+B4) + A1[a]B3[bcd] + A2[ab]B2[cd] + A3[abc]B1[d]
        rv.x = a4.x + fmaf(A1a, b3v.x, fmaf(a2x, b2v.x, a3x * b1v.x));
        rv.y = a4.y + fmaf(A1a, b3v.y, fmaf(a2x, b2v.y, a3x * b1v.y));
        rv.z = a4.z + fmaf(A1a, b3v.z, fmaf(a2x, b2v.z, a3x * b1v.z));
        rv.w = a4.w + fmaf(A1a, b3v.w, fmaf(a2x, b2v.w, a3x * b1v.w));
        // log correction
        rv.x = fmaf(Ac, v3.x, rv.x) + fmaf(Bv, v2.x, Cv * v1.x);
        rv.y = fmaf(Ac, v3.y, rv.y) + fmaf(Bv, v2.y, Cv * v1.y);
        rv.z = fmaf(Ac, v3.z, rv.z) + fmaf(Bv, v2.z, Cv * v1.z);
        rv.w = fmaf(Ac, v3.w, rv.w) + fmaf(Bv, v2.w, Cv * v1.w);
        *(float4*)(o4 + m0) = rv;
    }

    // level 3 (coalesced)
    {
        const float s1b = S1m[q], s1c = S1m[r];
        const float s2ab = S2m[a * 16 + q];
        const float s2bc = S2m[q * 16 + r];
        const float s3abc = S3m[a * 256 + tid];
        const float r3 = s3abc - 0.5f * fmaf(s1a, s2bc, s2ab * s1c)
                         + (1.f / 3.f) * s1a * s1b * s1c;
        outj[OFF_L3 + a * 256 + tid] = r3;
    }
    // level 2
    if (tid < 16) outj[OFF_L2 + a * 16 + tid] = fmaf(-0.5f * s1a, S1m[tid], S2m[a * 16 + tid]);
    // level 1
    if (tid == 0) outj[a] = s1a;
}

extern "C" void kernel_launch(void* const* d_in, const int* in_sizes, int n_in,
                              void* d_out, int out_size, void* d_ws, size_t ws_size,
                              hipStream_t stream) {
    const float* path = (const float*)d_in[0];
    float* out = (float*)d_out;
    float* ws = (float*)d_ws;
    float* sigA = ws + SIGA_OFF;
    float* sigB = ws + SIGB_OFF;

    k_scan<<<NB * 16, 128, 0, stream>>>(path, out, sigA, sigB);
    k_log<<<NB * 16, 256, 0, stream>>>(sigA, sigB, out);
}